// Round 1
// baseline (218.547 us; speedup 1.0000x reference)
//
#include <hip/hip_runtime.h>

// HoloAttentionV2: x@[Wk|Wv] (f16 MFMA) -> chunked complex scan (pos rotor +
// assoc phasor paths, f32) -> y@Wo (f16 MFMA) -> f32 out.
// Shapes: B=2 T=4096 DM=1024 H=16 D=64, M = B*T = 8192.

#define B_ 2
#define T_ 4096
#define DM_ 1024
#define H_ 16
#define D_ 64
#define M_ (B_*T_)
#define PHASE_SCALE 10.0f

typedef _Float16 f16;
typedef unsigned int u32;
typedef __attribute__((ext_vector_type(8))) _Float16 f16x8;
typedef __attribute__((ext_vector_type(4))) _Float16 f16x4;
typedef __attribute__((ext_vector_type(4))) float f32x4;

// ---------------- converts ----------------

__global__ void k_cvt_f32_f16(const float* __restrict__ src, f16* __restrict__ dst, int n) {
  int i = blockIdx.x * blockDim.x + threadIdx.x;
  int idx = i * 4;
  if (idx < n) {
    float4 v = *reinterpret_cast<const float4*>(src + idx);
    f16x4 o;
    o[0] = (f16)v.x; o[1] = (f16)v.y; o[2] = (f16)v.z; o[3] = (f16)v.w;
    *reinterpret_cast<f16x4*>(dst + idx) = o;
  }
}

// src: 1024x1024 f32 row-major (K x N). dst: N x K f16 row-major (row-stride 1024).
__global__ void k_transpose_cvt(const float* __restrict__ src, f16* __restrict__ dst) {
  __shared__ float tile[32][33];
  int bx = blockIdx.x;  // n tile
  int by = blockIdx.y;  // k tile
  int tx = threadIdx.x; // 0..31
  int ty = threadIdx.y; // 0..7
  #pragma unroll
  for (int r = 0; r < 32; r += 8)
    tile[ty + r][tx] = src[(size_t)(by * 32 + ty + r) * 1024 + bx * 32 + tx];
  __syncthreads();
  #pragma unroll
  for (int r = 0; r < 32; r += 8)
    dst[(size_t)(bx * 32 + ty + r) * 1024 + by * 32 + tx] = (f16)tile[tx][ty + r];
}

// ---------------- f16 MFMA GEMM (m97-style 128x128, BK=32) ----------------
// A: M x K row-major f16. Bt: N x K row-major f16 (i.e. B transposed).
// C: M x N row-major f32.  grid = (M/128, N/128), block = 256 (4 waves, 2x2).

__device__ __forceinline__ void gl2lds16(const void* g, void* l) {
  __builtin_amdgcn_global_load_lds((const __attribute__((address_space(1))) u32*)g,
                                   (__attribute__((address_space(3))) u32*)l, 16, 0, 0);
}

__launch_bounds__(256)
__global__ void k_gemm_f16(const f16* __restrict__ A, const f16* __restrict__ Bt,
                           float* __restrict__ C, int N, int K) {
  __shared__ f16 lA[128][32];
  __shared__ f16 lB[128][32];
  const int tid  = threadIdx.x;
  const int lane = tid & 63;
  const int wid  = tid >> 6;
  const int wr   = wid >> 1, wc = wid & 1;
  const int m0   = blockIdx.x * 128;
  const int n0   = blockIdx.y * 128;
  const int row_l = tid >> 2;        // 0..63 (wave-linear: LDS dest = base + lane*16)
  const int seg   = (tid & 3) * 8;   // halves offset within row (16B chunks)
  const int lr    = lane & 15;
  const int kofs  = (lane >> 4) * 8;

  f32x4 acc[4][4] = {};

  const f16* ga = A  + (size_t)(m0 + row_l) * K + seg;
  const f16* gb = Bt + (size_t)(n0 + row_l) * K + seg;

  for (int k0 = 0; k0 < K; k0 += 32) {
    gl2lds16(ga + k0,                 &lA[row_l][seg]);
    gl2lds16(ga + (size_t)64 * K + k0, &lA[64 + row_l][seg]);
    gl2lds16(gb + k0,                 &lB[row_l][seg]);
    gl2lds16(gb + (size_t)64 * K + k0, &lB[64 + row_l][seg]);
    __syncthreads();
    f16x8 af[4], bf[4];
    #pragma unroll
    for (int i = 0; i < 4; ++i)
      af[i] = *(const f16x8*)(&lA[wr * 64 + i * 16 + lr][kofs]);
    #pragma unroll
    for (int j = 0; j < 4; ++j)
      bf[j] = *(const f16x8*)(&lB[wc * 64 + j * 16 + lr][kofs]);
    #pragma unroll
    for (int i = 0; i < 4; ++i)
      #pragma unroll
      for (int j = 0; j < 4; ++j)
        acc[i][j] = __builtin_amdgcn_mfma_f32_16x16x32_f16(af[i], bf[j], acc[i][j], 0, 0, 0);
    __syncthreads();
  }

  // C/D layout (m89-verified): col = lane&15, row = (lane>>4)*4 + reg
  const int rb = (lane >> 4) * 4;
  #pragma unroll
  for (int i = 0; i < 4; ++i) {
    const int row = m0 + wr * 64 + i * 16 + rb;
    #pragma unroll
    for (int j = 0; j < 4; ++j) {
      const int col = n0 + wc * 64 + j * 16 + lr;
      #pragma unroll
      for (int r = 0; r < 4; ++r)
        C[(size_t)(row + r) * N + col] = acc[i][j][r];
    }
  }
}

// ---------------- scan (64 chunks of 64 t; lane = d, wave = chunk) ----------------
// kv: (M, 2048) f32; cols [0,1024) = k_real, [1024,2048) = v.
// tot/carry layout: [c][b][h][d] float4 {pos_re, pos_im, assoc_re, assoc_im}

__global__ void k_scan_part(const float* __restrict__ kv, const float* __restrict__ freqs,
                            float4* __restrict__ tot) {
  const int bid = blockIdx.x;
  const int cg = bid & 15;
  const int h  = (bid >> 4) & 15;
  const int b  = bid >> 8;
  const int w  = threadIdx.x >> 6;
  const int d  = threadIdx.x & 63;
  const int c  = cg * 4 + w;
  const int t0 = c * 64;
  const int base = h * 64 + d;
  const float f = freqs[base];

  float bc = 0.f, bs = 0.f;  // phasor of k[t-1]: binder = conj -> (bc, -bs)
  if (t0 > 0) {
    float krp = kv[(size_t)(b * T_ + t0 - 1) * 2048 + base];
    float th = PHASE_SCALE * krp;
    bs = __sinf(th); bc = __cosf(th);
  }
  float pr = 0.f, pi = 0.f, ar = 0.f, ai = 0.f;
  #pragma unroll 4
  for (int tt = 0; tt < 64; ++tt) {
    int t = t0 + tt;
    size_t row = (size_t)(b * T_ + t) * 2048;
    float v  = kv[row + 1024 + base];
    float kr = kv[row + base];
    // rotor phase t*f reduced mod 2pi in f64 (t*f up to ~26k rad)
    double rrev = (double)t * (double)f * 0.15915494309189535;
    rrev -= floor(rrev);
    float ph = (float)rrev * 6.28318530717958647692f;
    float sp = __sinf(ph), cp = __cosf(ph);
    pr += v * cp; pi += v * sp;
    ar += v * bc; ai -= v * bs;
    float th = PHASE_SCALE * kr;     // k_t phasor: probe now, binder next t
    bs = __sinf(th); bc = __cosf(th);
  }
  tot[((size_t)(c * 2 + b) * 16 + h) * 64 + d] = make_float4(pr, pi, ar, ai);
}

__global__ void k_scan_carry(const float4* __restrict__ tot, float4* __restrict__ carry) {
  const int h = blockIdx.x & 15;
  const int b = blockIdx.x >> 4;
  const int d = threadIdx.x;
  float pr = 0.f, pi = 0.f, ar = 0.f, ai = 0.f;
  for (int c = 0; c < 64; ++c) {
    size_t idx = ((size_t)(c * 2 + b) * 16 + h) * 64 + d;
    float4 tv = tot[idx];
    carry[idx] = make_float4(pr, pi, ar, ai);
    pr += tv.x; pi += tv.y; ar += tv.z; ai += tv.w;
  }
}

__global__ void k_scan_out(const float* __restrict__ kv, const float* __restrict__ freqs,
                           const float4* __restrict__ carry, const float* __restrict__ gate,
                           f16* __restrict__ y) {
  const int bid = blockIdx.x;
  const int cg = bid & 15;
  const int h  = (bid >> 4) & 15;
  const int b  = bid >> 8;
  const int w  = threadIdx.x >> 6;
  const int d  = threadIdx.x & 63;
  const int c  = cg * 4 + w;
  const int t0 = c * 64;
  const int base = h * 64 + d;
  const float f = freqs[base];
  const float gp = gate[2 * h], ga = gate[2 * h + 1];

  float4 cr = carry[((size_t)(c * 2 + b) * 16 + h) * 64 + d];
  float pr = cr.x, pi = cr.y, ar = cr.z, ai = cr.w;
  float bc = 0.f, bs = 0.f;
  if (t0 > 0) {
    float krp = kv[(size_t)(b * T_ + t0 - 1) * 2048 + base];
    float th = PHASE_SCALE * krp;
    bs = __sinf(th); bc = __cosf(th);
  }
  #pragma unroll 4
  for (int tt = 0; tt < 64; ++tt) {
    int t = t0 + tt;
    size_t row = (size_t)(b * T_ + t) * 2048;
    float v  = kv[row + 1024 + base];
    float kr = kv[row + base];
    double rrev = (double)t * (double)f * 0.15915494309189535;
    rrev -= floor(rrev);
    float ph = (float)rrev * 6.28318530717958647692f;
    float sp = __sinf(ph), cp = __cosf(ph);
    pr += v * cp; pi += v * sp;          // cum_pos += v * rotor
    ar += v * bc; ai -= v * bs;          // cum_assoc += v * conj(k[t-1])
    float th = PHASE_SCALE * kr;
    bs = __sinf(th); bc = __cosf(th);    // k_t phasor
    float inv = rsqrtf((float)(t + 1));
    float op = (pr * cp + pi * sp) * inv;   // Re(cum_pos * conj(rotor_t))
    float oa = (ar * bc - ai * bs) * inv;   // Re(cum_assoc * k_t)
    y[(size_t)(b * T_ + t) * 1024 + base] = (f16)(gp * op + ga * oa);
  }
}

// ---------------- launch ----------------

extern "C" void kernel_launch(void* const* d_in, const int* in_sizes, int n_in,
                              void* d_out, int out_size, void* d_ws, size_t ws_size,
                              hipStream_t stream) {
  const float* x     = (const float*)d_in[0];
  const float* Wk    = (const float*)d_in[1];
  const float* Wv    = (const float*)d_in[2];
  const float* Wo    = (const float*)d_in[3];
  const float* gate  = (const float*)d_in[4];
  const float* freqs = (const float*)d_in[5];
  float* out = (float*)d_out;

  char* ws = (char*)d_ws;
  size_t off = 0;
  auto alloc = [&](size_t bytes) { void* p = ws + off; off += (bytes + 255) & ~255ull; return p; };

  f16*    xh    = (f16*)   alloc((size_t)M_ * DM_ * sizeof(f16));   // reused as y after GEMM1
  f16*    Wkvt  = (f16*)   alloc((size_t)2048 * 1024 * sizeof(f16));
  f16*    Wot   = (f16*)   alloc((size_t)1024 * 1024 * sizeof(f16));
  float*  kvb   = (float*) alloc((size_t)M_ * 2048 * sizeof(float));
  float4* tot   = (float4*)alloc((size_t)64 * B_ * H_ * D_ * sizeof(float4));
  float4* carry = (float4*)alloc((size_t)64 * B_ * H_ * D_ * sizeof(float4));
  f16*    yh    = xh;  // safe alias: xh's last read (GEMM1) precedes y's first write (scan_out)

  // x -> fp16
  hipLaunchKernelGGL(k_cvt_f32_f16, dim3((M_ * DM_ / 4 + 255) / 256), dim3(256), 0, stream,
                     x, xh, M_ * DM_);
  // weights -> transposed fp16 (N-major for contiguous MFMA B-fragments)
  hipLaunchKernelGGL(k_transpose_cvt, dim3(32, 32), dim3(32, 8), 0, stream, Wk, Wkvt);
  hipLaunchKernelGGL(k_transpose_cvt, dim3(32, 32), dim3(32, 8), 0, stream, Wv, Wkvt + (size_t)1024 * 1024);
  hipLaunchKernelGGL(k_transpose_cvt, dim3(32, 32), dim3(32, 8), 0, stream, Wo, Wot);
  // [k_real | v] = x @ [Wk | Wv]
  hipLaunchKernelGGL(k_gemm_f16, dim3(64, 16), dim3(256), 0, stream, xh, Wkvt, kvb, 2048, 1024);
  // chunked complex scan
  hipLaunchKernelGGL(k_scan_part,  dim3(512), dim3(256), 0, stream, kvb, freqs, tot);
  hipLaunchKernelGGL(k_scan_carry, dim3(32),  dim3(64),  0, stream, tot, carry);
  hipLaunchKernelGGL(k_scan_out,   dim3(512), dim3(256), 0, stream, kvb, freqs, carry, gate, yh);
  // out = y @ Wo
  hipLaunchKernelGGL(k_gemm_f16, dim3(64, 8), dim3(256), 0, stream, yh, Wot, out, 1024, 1024);
}

// Round 2
// 203.097 us; speedup vs baseline: 1.0761x; 1.0761x over previous
//
#include <hip/hip_runtime.h>

// HoloAttentionV2: x@[Wk|Wv] (f16 MFMA, 256^2 8-phase) -> chunked complex scan
// (pos rotor incremental + assoc phasor, f32) -> y@Wo (same GEMM) -> f32 out.
// B=2 T=4096 DM=1024 H=16 D=64, M=8192, K=1024 for both GEMMs.

#define B_ 2
#define T_ 4096
#define H_ 16
#define D_ 64
#define M_ (B_*T_)
#define PHASE_SCALE 10.0f

typedef _Float16 f16;
typedef unsigned int u32;
typedef __attribute__((ext_vector_type(8))) _Float16 f16x8;
typedef __attribute__((ext_vector_type(4))) _Float16 f16x4;
typedef __attribute__((ext_vector_type(4))) float f32x4;

// ---------------- converts ----------------

__global__ void k_cvt_f32_f16(const float* __restrict__ src, f16* __restrict__ dst, int n) {
  int idx = (blockIdx.x * blockDim.x + threadIdx.x) * 4;
  if (idx < n) {
    float4 v = *reinterpret_cast<const float4*>(src + idx);
    f16x4 o;
    o[0] = (f16)v.x; o[1] = (f16)v.y; o[2] = (f16)v.z; o[3] = (f16)v.w;
    *reinterpret_cast<f16x4*>(dst + idx) = o;
  }
}

// src: 1024x1024 f32 row-major (K x N). dst: N x K f16 row-major.
__global__ void k_transpose_cvt(const float* __restrict__ src, f16* __restrict__ dst) {
  __shared__ float tile[32][33];
  int bx = blockIdx.x, by = blockIdx.y;
  int tx = threadIdx.x, ty = threadIdx.y;
  #pragma unroll
  for (int r = 0; r < 32; r += 8)
    tile[ty + r][tx] = src[(size_t)(by * 32 + ty + r) * 1024 + bx * 32 + tx];
  __syncthreads();
  #pragma unroll
  for (int r = 0; r < 32; r += 8)
    dst[(size_t)(bx * 32 + ty + r) * 1024 + by * 32 + tx] = (f16)tile[tx][ty + r];
}

// ---------------- 256x256 8-phase f16 MFMA GEMM, K=1024 (NT=16 K-tiles of 64) ----
// A: M x 1024 f16 row-major. Bt: N x 1024 f16 row-major (B transposed).
// Output col<1024 -> C32 (f32, stride 1024); col>=1024 -> C16 (f16, stride 1024).
// grid = (M/256, N/256), block = 512 (8 waves: wr=wid>>2 in {0,1}, wc=wid&3).
// Per wave per quadrant (ah,bh): rows ah*128+wr*64..+63, cols bh*128+wc*32..+31.
// LDS 128KiB: [buf0: A0 A1 B0 B1][buf1: ...], 16KB half-tiles, XOR-swizzled
// (chunk ^= row&7) via pre-swizzled global source (rule #21).

__device__ __forceinline__ void gl2lds16(const f16* g, char* l) {
  __builtin_amdgcn_global_load_lds((const __attribute__((address_space(1))) u32*)g,
                                   (__attribute__((address_space(3))) u32*)l, 16, 0, 0);
}

#define S_BAR() __builtin_amdgcn_s_barrier()
#define WAIT_LGKM0() do { asm volatile("s_waitcnt lgkmcnt(0)" ::: "memory"); \
                          __builtin_amdgcn_sched_barrier(0); } while (0)
#define WAIT_VM(n) asm volatile("s_waitcnt vmcnt(" #n ")" ::: "memory")

// stage one 128x64 half-tile: 2 x global_load_lds per thread (rows rsub, rsub+64)
#define STAGE(gp, ldsoff, kkt) do { \
  gl2lds16((gp) + (size_t)(kkt) * 64,               smem + (ldsoff) + tid * 16); \
  gl2lds16((gp) + (size_t)(kkt) * 64 + 64 * 1024,   smem + (ldsoff) + 8192 + tid * 16); \
} while (0)

#define PHASE(AH, BH, READ_A, VMW, STG) do { \
  if (READ_A) { \
    _Pragma("unroll") for (int mi = 0; mi < 4; ++mi) \
    _Pragma("unroll") for (int kk = 0; kk < 2; ++kk) \
      aF[mi][kk] = *(const f16x8*)(smem + curbuf + (AH) * 16384 + offA[mi][kk]); \
  } \
  _Pragma("unroll") for (int nj = 0; nj < 2; ++nj) \
  _Pragma("unroll") for (int kk = 0; kk < 2; ++kk) \
    bF[nj][kk] = *(const f16x8*)(smem + curbuf + 32768 + (BH) * 16384 + offB[nj][kk]); \
  STG; \
  S_BAR(); \
  WAIT_LGKM0(); \
  __builtin_amdgcn_s_setprio(1); \
  _Pragma("unroll") for (int mi = 0; mi < 4; ++mi) \
  _Pragma("unroll") for (int nj = 0; nj < 2; ++nj) \
  _Pragma("unroll") for (int kk = 0; kk < 2; ++kk) \
    acc[(AH) * 2 + (BH)][mi][nj] = __builtin_amdgcn_mfma_f32_16x16x32_f16( \
        aF[mi][kk], bF[nj][kk], acc[(AH) * 2 + (BH)][mi][nj], 0, 0, 0); \
  __builtin_amdgcn_s_setprio(0); \
  VMW; \
  S_BAR(); \
} while (0)

__launch_bounds__(512, 1)
__global__ void k_gemm8(const f16* __restrict__ A, const f16* __restrict__ Bt,
                        float* __restrict__ C32, f16* __restrict__ C16) {
  extern __shared__ char smem[];
  const int tid  = threadIdx.x;
  const int lane = tid & 63;
  const int wid  = tid >> 6;
  const int wr   = wid >> 2, wc = wid & 3;
  const int lr   = lane & 15, hi = lane >> 4;
  const int m0   = blockIdx.x * 256;
  const int n0   = blockIdx.y * 256;

  // staging source (pre-swizzled column chunk so linear LDS image is swizzled)
  const int rsub = tid >> 3;                         // 0..63 row in 64-row group
  const int csw  = ((tid & 7) ^ (rsub & 7)) * 8;     // swizzled 8-elem chunk
  const f16* gA0 = A  + (size_t)(m0 + rsub) * 1024 + csw;
  const f16* gA1 = gA0 + (size_t)128 * 1024;
  const f16* gB0 = Bt + (size_t)(n0 + rsub) * 1024 + csw;
  const f16* gB1 = gB0 + (size_t)128 * 1024;

  // LDS read byte-offsets within a half-tile (row*128, chunk^=(row&7))
  int offA[4][2], offB[2][2];
  #pragma unroll
  for (int mi = 0; mi < 4; ++mi)
    #pragma unroll
    for (int kk = 0; kk < 2; ++kk) {
      int row = wr * 64 + mi * 16 + lr;
      offA[mi][kk] = row * 128 + (((kk * 4 + hi) ^ (row & 7)) << 4);
    }
  #pragma unroll
  for (int nj = 0; nj < 2; ++nj)
    #pragma unroll
    for (int kk = 0; kk < 2; ++kk) {
      int row = wc * 32 + nj * 16 + lr;
      offB[nj][kk] = row * 128 + (((kk * 4 + hi) ^ (row & 7)) << 4);
    }

  f32x4 acc[4][4][2] = {};   // [ah*2+bh][mi][nj]
  f16x8 aF[4][2], bF[2][2];

  // prologue: A0(0) B0(0) A1(0) A0(1) B1(0) B0(1)  (order matters for vmcnt math)
  STAGE(gA0, 0,     0);
  STAGE(gB0, 32768, 0);
  STAGE(gA1, 16384, 0);
  STAGE(gA0, 65536, 1);
  STAGE(gB1, 49152, 0);
  STAGE(gB0, 98304, 1);
  WAIT_VM(8);                 // A0(0), B0(0) landed (all waves barrier below)
  S_BAR();

  // steady state: per K-tile kt stage A1(kt+1)@p0, A0(kt+2)@p1, B1(kt+1)@p2,
  // B0(kt+2)@p3; waits (before end-barrier): p0 vm4 (B1(kt) landed for p1),
  // p1 vm10 (A1(kt) for p2), p3 vm8 (A0,B0(kt+1) for next p0).
  for (int kt = 0; kt < 14; ++kt) {
    const int curbuf = (kt & 1) * 65536;
    const int nxtbuf = curbuf ^ 65536;
    PHASE(0, 0, 1, WAIT_VM(4),  STAGE(gA1, nxtbuf + 16384, kt + 1));
    PHASE(0, 1, 0, WAIT_VM(10), STAGE(gA0, curbuf + 0,     kt + 2));
    PHASE(1, 0, 1, (void)0,     STAGE(gB1, nxtbuf + 49152, kt + 1));
    PHASE(1, 1, 0, WAIT_VM(8),  STAGE(gB0, curbuf + 32768, kt + 2));
  }
  { // kt = 14: no kt+2 stages
    const int curbuf = 0, nxtbuf = 65536;
    PHASE(0, 0, 1, WAIT_VM(4), STAGE(gA1, nxtbuf + 16384, 15));
    PHASE(0, 1, 0, WAIT_VM(8), (void)0);
    PHASE(1, 0, 1, (void)0,    STAGE(gB1, nxtbuf + 49152, 15));
    PHASE(1, 1, 0, WAIT_VM(4), (void)0);
  }
  { // kt = 15: no stages
    const int curbuf = 65536;
    PHASE(0, 0, 1, WAIT_VM(0), (void)0);
    PHASE(0, 1, 0, (void)0,    (void)0);
    PHASE(1, 0, 1, (void)0,    (void)0);
    PHASE(1, 1, 0, (void)0,    (void)0);
  }

  // epilogue: C/D layout col=lane&15, row=(lane>>4)*4+reg (m89-verified)
  const int rb = hi * 4;
  #pragma unroll
  for (int ah = 0; ah < 2; ++ah)
    #pragma unroll
    for (int bh = 0; bh < 2; ++bh)
      #pragma unroll
      for (int mi = 0; mi < 4; ++mi)
        #pragma unroll
        for (int nj = 0; nj < 2; ++nj) {
          f32x4 a4 = acc[ah * 2 + bh][mi][nj];
          const int row = m0 + ah * 128 + wr * 64 + mi * 16 + rb;
          const int col = n0 + bh * 128 + wc * 32 + nj * 16 + lr;
          if (col < 1024) {
            #pragma unroll
            for (int r = 0; r < 4; ++r)
              C32[(size_t)(row + r) * 1024 + col] = a4[r];
          } else {
            #pragma unroll
            for (int r = 0; r < 4; ++r)
              C16[(size_t)(row + r) * 1024 + (col - 1024)] = (f16)a4[r];
          }
        }
}

// ---------------- scan: 128 chunks x 32 t; lane = d, wave = chunk ----------------
// kf: (M,1024) f32 k_real; vh: (M,1024) f16 v.
// tot/carry: [c][b][h][d] float4 {pos_re, pos_im, assoc_re, assoc_im}, c in [0,128)

__global__ void k_scan_part(const float* __restrict__ kf, const f16* __restrict__ vh,
                            const float* __restrict__ freqs, float4* __restrict__ tot) {
  const int bid = blockIdx.x;
  const int cg = bid & 31;
  const int h  = (bid >> 5) & 15;
  const int b  = bid >> 9;
  const int w  = threadIdx.x >> 6;
  const int d  = threadIdx.x & 63;
  const int c  = cg * 4 + w;
  const int t0 = c * 32;
  const int col = h * 64 + d;
  const float f = freqs[col];

  float bc = 0.f, bs = 0.f;               // binder = conj(k[t-1]) -> (bc,-bs)
  if (t0 > 0) {
    float krp = kf[(size_t)(b * T_ + t0 - 1) * 1024 + col];
    __sincosf(PHASE_SCALE * krp, &bs, &bc);
  }
  // rotor e^{i t f}: f64 anchor at t0, then incremental complex-mul by e^{i f}
  double rev = (double)t0 * (double)f * 0.15915494309189535;
  rev -= floor(rev);
  float ph = (float)rev * 6.28318530717958647692f;
  float ri, rc; __sincosf(ph, &ri, &rc);
  float sf, cf; __sincosf(f, &sf, &cf);

  float pr = 0.f, pi = 0.f, ar = 0.f, ai = 0.f;
  #pragma unroll 8
  for (int tt = 0; tt < 32; ++tt) {
    size_t row = (size_t)(b * T_ + t0 + tt) * 1024 + col;
    float v  = (float)vh[row];
    float kr = kf[row];
    pr = fmaf(v, rc, pr); pi = fmaf(v, ri, pi);
    ar = fmaf(v, bc, ar); ai = fmaf(-v, bs, ai);
    __sincosf(PHASE_SCALE * kr, &bs, &bc);       // k_t phasor -> binder for t+1
    float nrc = rc * cf - ri * sf;
    ri = rc * sf + ri * cf; rc = nrc;
  }
  tot[((size_t)(c * 2 + b) * 16 + h) * 64 + d] = make_float4(pr, pi, ar, ai);
}

__global__ void k_scan_carry(const float4* __restrict__ tot, float4* __restrict__ carry) {
  const int h = blockIdx.x & 15;
  const int b = blockIdx.x >> 4;
  const int d = threadIdx.x;
  float pr = 0.f, pi = 0.f, ar = 0.f, ai = 0.f;
  for (int c = 0; c < 128; ++c) {
    size_t idx = ((size_t)(c * 2 + b) * 16 + h) * 64 + d;
    float4 tv = tot[idx];
    carry[idx] = make_float4(pr, pi, ar, ai);
    pr += tv.x; pi += tv.y; ar += tv.z; ai += tv.w;
  }
}

__global__ void k_scan_out(const float* __restrict__ kf, const f16* __restrict__ vh,
                           const float* __restrict__ freqs, const float4* __restrict__ carry,
                           const float* __restrict__ gate, f16* __restrict__ y) {
  const int bid = blockIdx.x;
  const int cg = bid & 31;
  const int h  = (bid >> 5) & 15;
  const int b  = bid >> 9;
  const int w  = threadIdx.x >> 6;
  const int d  = threadIdx.x & 63;
  const int c  = cg * 4 + w;
  const int t0 = c * 32;
  const int col = h * 64 + d;
  const float f = freqs[col];
  const float gp = gate[2 * h], ga = gate[2 * h + 1];

  float4 cr = carry[((size_t)(c * 2 + b) * 16 + h) * 64 + d];
  float pr = cr.x, pi = cr.y, ar = cr.z, ai = cr.w;
  float bc = 0.f, bs = 0.f;
  if (t0 > 0) {
    float krp = kf[(size_t)(b * T_ + t0 - 1) * 1024 + col];
    __sincosf(PHASE_SCALE * krp, &bs, &bc);
  }
  double rev = (double)t0 * (double)f * 0.15915494309189535;
  rev -= floor(rev);
  float ph = (float)rev * 6.28318530717958647692f;
  float ri, rc; __sincosf(ph, &ri, &rc);
  float sf, cf; __sincosf(f, &sf, &cf);

  #pragma unroll 8
  for (int tt = 0; tt < 32; ++tt) {
    int t = t0 + tt;
    size_t row = (size_t)(b * T_ + t) * 1024 + col;
    float v  = (float)vh[row];
    float kr = kf[row];
    pr = fmaf(v, rc, pr); pi = fmaf(v, ri, pi);    // cum_pos += v * rotor
    ar = fmaf(v, bc, ar); ai = fmaf(-v, bs, ai);   // cum_assoc += v * conj(k[t-1])
    float kc, ks; __sincosf(PHASE_SCALE * kr, &ks, &kc);   // k_t phasor (probe)
    float inv = rsqrtf((float)(t + 1));
    float op = fmaf(pr, rc, pi * ri) * inv;        // Re(cum_pos * conj(rotor))
    float oa = fmaf(ar, kc, -(ai * ks)) * inv;     // Re(cum_assoc * k_t)
    y[row] = (f16)(gp * op + ga * oa);
    bs = ks; bc = kc;                              // binder for t+1
    float nrc = rc * cf - ri * sf;
    ri = rc * sf + ri * cf; rc = nrc;
  }
}

// ---------------- launch ----------------

extern "C" void kernel_launch(void* const* d_in, const int* in_sizes, int n_in,
                              void* d_out, int out_size, void* d_ws, size_t ws_size,
                              hipStream_t stream) {
  const float* x     = (const float*)d_in[0];
  const float* Wk    = (const float*)d_in[1];
  const float* Wv    = (const float*)d_in[2];
  const float* Wo    = (const float*)d_in[3];
  const float* gate  = (const float*)d_in[4];
  const float* freqs = (const float*)d_in[5];
  float* out = (float*)d_out;

  char* ws = (char*)d_ws;
  size_t off = 0;
  auto alloc = [&](size_t bytes) { void* p = ws + off; off += (bytes + 255) & ~255ull; return p; };

  f16*    xh    = (f16*)   alloc((size_t)M_ * 1024 * sizeof(f16));   // aliased as y later
  f16*    Wkvt  = (f16*)   alloc((size_t)2048 * 1024 * sizeof(f16));
  f16*    Wot   = (f16*)   alloc((size_t)1024 * 1024 * sizeof(f16));
  float*  kf    = (float*) alloc((size_t)M_ * 1024 * sizeof(float));
  f16*    vh    = (f16*)   alloc((size_t)M_ * 1024 * sizeof(f16));
  float4* tot   = (float4*)alloc((size_t)128 * B_ * H_ * D_ * sizeof(float4));
  float4* carry = (float4*)alloc((size_t)128 * B_ * H_ * D_ * sizeof(float4));
  f16*    yh    = xh;  // xh last read by GEMM1 (before scan_out writes y)

  hipFuncSetAttribute(reinterpret_cast<const void*>(&k_gemm8),
                      hipFuncAttributeMaxDynamicSharedMemorySize, 131072);

  hipLaunchKernelGGL(k_cvt_f32_f16, dim3((M_ * 1024 / 4 + 255) / 256), dim3(256), 0, stream,
                     x, xh, M_ * 1024);
  hipLaunchKernelGGL(k_transpose_cvt, dim3(32, 32), dim3(32, 8), 0, stream, Wk, Wkvt);
  hipLaunchKernelGGL(k_transpose_cvt, dim3(32, 32), dim3(32, 8), 0, stream, Wv, Wkvt + (size_t)1024 * 1024);
  hipLaunchKernelGGL(k_transpose_cvt, dim3(32, 32), dim3(32, 8), 0, stream, Wo, Wot);
  // [k_real | v] = x @ [Wk | Wv]  (cols<1024 -> kf f32, cols>=1024 -> vh f16)
  hipLaunchKernelGGL(k_gemm8, dim3(32, 8), dim3(512), 131072, stream, xh, Wkvt, kf, vh);
  // chunked complex scan
  hipLaunchKernelGGL(k_scan_part,  dim3(1024), dim3(256), 0, stream, kf, vh, freqs, tot);
  hipLaunchKernelGGL(k_scan_carry, dim3(32),   dim3(64),  0, stream, tot, carry);
  hipLaunchKernelGGL(k_scan_out,   dim3(1024), dim3(256), 0, stream, kf, vh, freqs, carry, gate, yh);
  // out = y @ Wo
  hipLaunchKernelGGL(k_gemm8, dim3(32, 4), dim3(512), 131072, stream, yh, Wot, out, nullptr);
}

// Round 4
// 199.963 us; speedup vs baseline: 1.0929x; 1.0157x over previous
//
#include <hip/hip_runtime.h>

// HoloAttentionV2: prep (cvt+transposes, 1 kernel) -> x@[Wk|Wv] (256^2 8-phase
// f16 MFMA) -> scan_part -> scan_out(+in-kernel chunk prefix) -> y@Wo
// (128-row variant, full-GPU grid). 5 launches.
// B=2 T=4096 DM=1024 H=16 D=64, M=8192, K=1024 both GEMMs.

#define B_ 2
#define T_ 4096
#define H_ 16
#define D_ 64
#define M_ (B_*T_)
#define PHASE_SCALE 10.0f

typedef _Float16 f16;
typedef unsigned int u32;
typedef __attribute__((ext_vector_type(8))) _Float16 f16x8;
typedef __attribute__((ext_vector_type(4))) _Float16 f16x4;
typedef __attribute__((ext_vector_type(4))) float f32x4;

// ---------------- prep: z<3 weight transpose-cvt, z==3 x cvt ----------------
// grid (32,32,4), block (32,8)

__global__ void k_prep(const float* __restrict__ x, const float* __restrict__ Wk,
                       const float* __restrict__ Wv, const float* __restrict__ Wo,
                       f16* __restrict__ xh, f16* __restrict__ Wkvt, f16* __restrict__ Wot) {
  __shared__ float tile[32][33];
  const int z = blockIdx.z;
  const int tx = threadIdx.x, ty = threadIdx.y;
  if (z == 3) {              // x (8M f32) -> f16, float4-vectorized grid-stride
    const int blk = blockIdx.y * 32 + blockIdx.x;          // 0..1023
    const size_t base = (size_t)blk * 256 + ty * 32 + tx;  // float4 index
    #pragma unroll
    for (int i = 0; i < 8; ++i) {
      size_t idx = (base + (size_t)i * 262144) * 4;
      float4 v = *reinterpret_cast<const float4*>(x + idx);
      f16x4 o; o[0] = (f16)v.x; o[1] = (f16)v.y; o[2] = (f16)v.z; o[3] = (f16)v.w;
      *reinterpret_cast<f16x4*>(xh + idx) = o;
    }
    return;
  }
  const float* src = (z == 0) ? Wk : (z == 1) ? Wv : Wo;
  f16* dst = (z == 0) ? Wkvt : (z == 1) ? (Wkvt + (size_t)1024 * 1024) : Wot;
  const int bx = blockIdx.x, by = blockIdx.y;
  #pragma unroll
  for (int r = 0; r < 32; r += 8)
    tile[ty + r][tx] = src[(size_t)(by * 32 + ty + r) * 1024 + bx * 32 + tx];
  __syncthreads();
  #pragma unroll
  for (int r = 0; r < 32; r += 8)
    dst[(size_t)(bx * 32 + ty + r) * 1024 + by * 32 + tx] = (f16)tile[tx][ty + r];
}

// ---------------- 8-phase f16 MFMA GEMM, K=1024 (16 K-tiles of 64) ----------
// template MI: fragments/quadrant. MI=4 -> BM=256; MI=2 -> BM=128. BN=256.
// A: M x 1024 f16. Bt: N x 1024 f16 (B^T). C col<1024 -> C32 f32; else C16 f16.
// 8 waves (wr = wid>>2, wc = wid&3); per wave per quadrant (ah,bh):
//   rows ah*AH_R + wr*(MI*16) + mi*16, cols bh*128 + wc*32 + nj*16.
// LDS per buf: [A0|A1|B0|B1], A halves AHB=MI*4KB, B halves 16KB; double-buffered.
// XOR-swizzle (chunk ^= row&7) via pre-swizzled global source; linear LDS dest.

__device__ __forceinline__ void gl2lds16(const f16* g, char* l) {
  __builtin_amdgcn_global_load_lds((const __attribute__((address_space(1))) u32*)g,
                                   (__attribute__((address_space(3))) u32*)l, 16, 0, 0);
}

#define S_BAR() __builtin_amdgcn_s_barrier()
#define WAIT_LGKM0() do { asm volatile("s_waitcnt lgkmcnt(0)" ::: "memory"); \
                          __builtin_amdgcn_sched_barrier(0); } while (0)
#define WAIT_VM(n) asm volatile("s_waitcnt vmcnt(" #n ")" ::: "memory")

// A half-tile stage: MI/2 gl2lds16 per thread (rows tid>>3 [+64])
#define STAGE_A(gp, ldsoff, kkt) do { \
  gl2lds16((gp) + (size_t)(kkt) * 64, smem + (ldsoff) + tid * 16); \
  if constexpr (MI == 4) \
    gl2lds16((gp) + (size_t)(kkt) * 64 + 64 * 1024, smem + (ldsoff) + 8192 + tid * 16); \
} while (0)
// B half-tile stage: always 2 (128 rows)
#define STAGE_B(gp, ldsoff, kkt) do { \
  gl2lds16((gp) + (size_t)(kkt) * 64, smem + (ldsoff) + tid * 16); \
  gl2lds16((gp) + (size_t)(kkt) * 64 + 64 * 1024, smem + (ldsoff) + 8192 + tid * 16); \
} while (0)

#define PHASE(AH, BH, READ_A, READ_B, VMW, STG) do { \
  if (READ_A) { \
    _Pragma("unroll") for (int mi = 0; mi < MI; ++mi) \
    _Pragma("unroll") for (int kk = 0; kk < 2; ++kk) \
      aF[mi][kk] = *(const f16x8*)(smem + curbuf + (AH) * AHB + offA[mi][kk]); \
  } \
  if (READ_B) { \
    _Pragma("unroll") for (int nj = 0; nj < 2; ++nj) \
    _Pragma("unroll") for (int kk = 0; kk < 2; ++kk) \
      bF[BH][nj][kk] = *(const f16x8*)(smem + curbuf + 2 * AHB + (BH) * 16384 + offB[nj][kk]); \
  } \
  STG; \
  S_BAR(); \
  WAIT_LGKM0(); \
  __builtin_amdgcn_s_setprio(1); \
  _Pragma("unroll") for (int mi = 0; mi < MI; ++mi) \
  _Pragma("unroll") for (int nj = 0; nj < 2; ++nj) \
  _Pragma("unroll") for (int kk = 0; kk < 2; ++kk) \
    acc[(AH) * 2 + (BH)][mi][nj] = __builtin_amdgcn_mfma_f32_16x16x32_f16( \
        aF[mi][kk], bF[BH][nj][kk], acc[(AH) * 2 + (BH)][mi][nj], 0, 0, 0); \
  __builtin_amdgcn_s_setprio(0); \
  VMW; \
  S_BAR(); \
} while (0)

template<int MI>
__launch_bounds__(512, 1)
__global__ void k_gemm8(const f16* __restrict__ A, const f16* __restrict__ Bt,
                        float* __restrict__ C32, f16* __restrict__ C16) {
  extern __shared__ char smem[];
  constexpr int AH_R = MI * 32;          // A half-tile rows
  constexpr int AHB  = AH_R * 128;       // A half-tile bytes
  constexpr int BUFSZ = 2 * AHB + 32768; // per-buffer bytes
  const int tid  = threadIdx.x;
  const int lane = tid & 63;
  const int wid  = tid >> 6;
  const int wr   = wid >> 2, wc = wid & 3;
  const int lr   = lane & 15, hi = lane >> 4;
  const int m0   = blockIdx.x * (MI * 64);
  const int n0   = blockIdx.y * 256;

  const int rsub = tid >> 3;                      // 0..63
  const int csw  = ((tid & 7) ^ (rsub & 7)) * 8;  // pre-swizzled chunk
  const f16* gA0 = A  + (size_t)(m0 + rsub) * 1024 + csw;
  const f16* gA1 = gA0 + (size_t)AH_R * 1024;
  const f16* gB0 = Bt + (size_t)(n0 + rsub) * 1024 + csw;
  const f16* gB1 = gB0 + (size_t)128 * 1024;

  int offA[MI][2], offB[2][2];
  #pragma unroll
  for (int mi = 0; mi < MI; ++mi)
    #pragma unroll
    for (int kk = 0; kk < 2; ++kk) {
      int row = wr * (MI * 16) + mi * 16 + lr;
      offA[mi][kk] = row * 128 + (((kk * 4 + hi) ^ (row & 7)) << 4);
    }
  #pragma unroll
  for (int nj = 0; nj < 2; ++nj)
    #pragma unroll
    for (int kk = 0; kk < 2; ++kk) {
      int row = wc * 32 + nj * 16 + lr;
      offB[nj][kk] = row * 128 + (((kk * 4 + hi) ^ (row & 7)) << 4);
    }

  f32x4 acc[4][MI][2] = {};
  f16x8 aF[MI][2], bF[2][2][2];   // bF cached per K-tile (read p0/p1, reuse p2/p3)

  // prologue stages (instr counts: A=MI/2, B=2):
  // A0(0) B0(0) A1(0) A0(1) B1(0) B0(1); wait drains A0(0),B0(0).
  STAGE_A(gA0, 0,            0);
  STAGE_B(gB0, 2 * AHB,      0);
  STAGE_A(gA1, AHB,          0);
  STAGE_A(gA0, BUFSZ,        1);
  STAGE_B(gB1, 2 * AHB + 16384, 0);
  STAGE_B(gB0, BUFSZ + 2 * AHB, 1);
  if constexpr (MI == 4) WAIT_VM(8); else WAIT_VM(6);
  S_BAR();

  // steady state (instruction-exact vmcnt, traced):
  // MI=4: invariant queue at kt start = [A1(kt)2, A0(kt+1)2, B1(kt)2, B0(kt+1)2];
  //       p0 +A1(kt+1) -> vm4 drains A1(kt),A0(kt+1),B1(kt); p3 Q=10 -> vm8 drains B0(kt+1).
  // MI=2: counts [1,1,2,2]; p0 +1 -> vm3; p3 Q=8 -> vm6.
  for (int kt = 0; kt < 14; ++kt) {
    const int curbuf = (kt & 1) * BUFSZ;
    const int nxtbuf = curbuf ^ BUFSZ;
    PHASE(0, 0, 1, 1, if constexpr (MI == 4) WAIT_VM(4); else WAIT_VM(3),
          STAGE_A(gA1, nxtbuf + AHB, kt + 1));
    PHASE(0, 1, 0, 1, (void)0, STAGE_A(gA0, curbuf, kt + 2));
    PHASE(1, 0, 1, 0, (void)0, STAGE_B(gB1, nxtbuf + 2 * AHB + 16384, kt + 1));
    PHASE(1, 1, 0, 0, if constexpr (MI == 4) WAIT_VM(8); else WAIT_VM(6),
          STAGE_B(gB0, curbuf + 2 * AHB, kt + 2));
  }
  { // kt = 14: stage only kt+1 halves
    const int curbuf = 0, nxtbuf = BUFSZ;
    PHASE(0, 0, 1, 1, if constexpr (MI == 4) WAIT_VM(4); else WAIT_VM(3),
          STAGE_A(gA1, nxtbuf + AHB, 15));
    PHASE(0, 1, 0, 1, (void)0, (void)0);
    PHASE(1, 0, 1, 0, (void)0, STAGE_B(gB1, nxtbuf + 2 * AHB + 16384, 15));
    PHASE(1, 1, 0, 0, if constexpr (MI == 4) WAIT_VM(4); else WAIT_VM(3), (void)0);
  }
  { // kt = 15
    const int curbuf = BUFSZ;
    PHASE(0, 0, 1, 1, WAIT_VM(0), (void)0);
    PHASE(0, 1, 0, 1, (void)0, (void)0);
    PHASE(1, 0, 1, 0, (void)0, (void)0);
    PHASE(1, 1, 0, 0, (void)0, (void)0);
  }

  // epilogue: C/D layout col=lane&15, row=(lane>>4)*4+reg (m89-verified)
  const int rb = hi * 4;
  #pragma unroll
  for (int ah = 0; ah < 2; ++ah)
    #pragma unroll
    for (int bh = 0; bh < 2; ++bh)
      #pragma unroll
      for (int mi = 0; mi < MI; ++mi)
        #pragma unroll
        for (int nj = 0; nj < 2; ++nj) {
          f32x4 a4 = acc[ah * 2 + bh][mi][nj];
          const int row = m0 + ah * AH_R + wr * (MI * 16) + mi * 16 + rb;
          const int col = n0 + bh * 128 + wc * 32 + nj * 16 + lr;
          if (col < 1024) {
            #pragma unroll
            for (int r = 0; r < 4; ++r)
              C32[(size_t)(row + r) * 1024 + col] = a4[r];
          } else {
            #pragma unroll
            for (int r = 0; r < 4; ++r)
              C16[(size_t)(row + r) * 1024 + (col - 1024)] = (f16)a4[r];
          }
        }
}

// ---------------- scan: 64 chunks x 64 t; lane = d, wave = chunk -------------
// kf: (M,1024) f32 k_real; vh: (M,1024) f16 v.
// tot: [c][b][h][d] float4 {pos_re, pos_im, assoc_re, assoc_im}, c in [0,64)

__global__ void k_scan_part(const float* __restrict__ kf, const f16* __restrict__ vh,
                            const float* __restrict__ freqs, float4* __restrict__ tot) {
  const int bid = blockIdx.x;
  const int cg = bid & 15;
  const int h  = (bid >> 4) & 15;
  const int b  = bid >> 8;
  const int w  = threadIdx.x >> 6;
  const int d  = threadIdx.x & 63;
  const int c  = cg * 4 + w;
  const int t0 = c * 64;
  const int col = h * 64 + d;
  const float f = freqs[col];

  float bc = 0.f, bs = 0.f;              // binder = conj(k[t-1]) -> (bc,-bs)
  if (t0 > 0) {
    float krp = kf[(size_t)(b * T_ + t0 - 1) * 1024 + col];
    __sincosf(PHASE_SCALE * krp, &bs, &bc);
  }
  double rev = (double)t0 * (double)f * 0.15915494309189535;  // f64 anchor
  rev -= floor(rev);
  float ph = (float)rev * 6.28318530717958647692f;
  float ri, rc; __sincosf(ph, &ri, &rc);
  float sf, cf; __sincosf(f, &sf, &cf);

  float pr = 0.f, pi = 0.f, ar = 0.f, ai = 0.f;
  #pragma unroll 4
  for (int tt = 0; tt < 64; ++tt) {
    size_t row = (size_t)(b * T_ + t0 + tt) * 1024 + col;
    float v  = (float)vh[row];
    float kr = kf[row];
    pr = fmaf(v, rc, pr); pi = fmaf(v, ri, pi);
    ar = fmaf(v, bc, ar); ai = fmaf(-v, bs, ai);
    __sincosf(PHASE_SCALE * kr, &bs, &bc);
    float nrc = rc * cf - ri * sf;
    ri = rc * sf + ri * cf; rc = nrc;
  }
  tot[((size_t)(c * 2 + b) * 16 + h) * 64 + d] = make_float4(pr, pi, ar, ai);
}

__global__ void k_scan_out(const float* __restrict__ kf, const f16* __restrict__ vh,
                           const float* __restrict__ freqs, const float4* __restrict__ tot,
                           const float* __restrict__ gate, f16* __restrict__ y) {
  const int bid = blockIdx.x;
  const int cg = bid & 15;
  const int h  = (bid >> 4) & 15;
  const int b  = bid >> 8;
  const int w  = threadIdx.x >> 6;
  const int d  = threadIdx.x & 63;
  const int c  = cg * 4 + w;
  const int t0 = c * 64;
  const int col = h * 64 + d;
  const float f = freqs[col];
  const float gp = gate[2 * h], ga = gate[2 * h + 1];

  // chunk-prefix from tot (coalesced L2 reads; wave-uniform trip count)
  float pr = 0.f, pi = 0.f, ar = 0.f, ai = 0.f;
  for (int cc = 0; cc < c; ++cc) {
    float4 tv = tot[((size_t)(cc * 2 + b) * 16 + h) * 64 + d];
    pr += tv.x; pi += tv.y; ar += tv.z; ai += tv.w;
  }

  float bc = 0.f, bs = 0.f;
  if (t0 > 0) {
    float krp = kf[(size_t)(b * T_ + t0 - 1) * 1024 + col];
    __sincosf(PHASE_SCALE * krp, &bs, &bc);
  }
  double rev = (double)t0 * (double)f * 0.15915494309189535;
  rev -= floor(rev);
  float ph = (float)rev * 6.28318530717958647692f;
  float ri, rc; __sincosf(ph, &ri, &rc);
  float sf, cf; __sincosf(f, &sf, &cf);

  #pragma unroll 4
  for (int tt = 0; tt < 64; ++tt) {
    int t = t0 + tt;
    size_t row = (size_t)(b * T_ + t) * 1024 + col;
    float v  = (float)vh[row];
    float kr = kf[row];
    pr = fmaf(v, rc, pr); pi = fmaf(v, ri, pi);     // cum_pos += v * rotor
    ar = fmaf(v, bc, ar); ai = fmaf(-v, bs, ai);    // cum_assoc += v * conj(k[t-1])
    float kc, ks; __sincosf(PHASE_SCALE * kr, &ks, &kc);
    float inv = rsqrtf((float)(t + 1));
    float op = fmaf(pr, rc, pi * ri) * inv;         // Re(cum_pos * conj(rotor))
    float oa = fmaf(ar, kc, -(ai * ks)) * inv;      // Re(cum_assoc * k_t)
    y[row] = (f16)(gp * op + ga * oa);
    bs = ks; bc = kc;
    float nrc = rc * cf - ri * sf;
    ri = rc * sf + ri * cf; rc = nrc;
  }
}

// ---------------- launch ----------------

extern "C" void kernel_launch(void* const* d_in, const int* in_sizes, int n_in,
                              void* d_out, int out_size, void* d_ws, size_t ws_size,
                              hipStream_t stream) {
  const float* x     = (const float*)d_in[0];
  const float* Wk    = (const float*)d_in[1];
  const float* Wv    = (const float*)d_in[2];
  const float* Wo    = (const float*)d_in[3];
  const float* gate  = (const float*)d_in[4];
  const float* freqs = (const float*)d_in[5];
  float* out = (float*)d_out;

  char* ws = (char*)d_ws;
  size_t off = 0;
  auto alloc = [&](size_t bytes) { void* p = ws + off; off += (bytes + 255) & ~255ull; return p; };

  f16*    xh   = (f16*)   alloc((size_t)M_ * 1024 * sizeof(f16));   // aliased as y
  f16*    Wkvt = (f16*)   alloc((size_t)2048 * 1024 * sizeof(f16));
  f16*    Wot  = (f16*)   alloc((size_t)1024 * 1024 * sizeof(f16));
  float*  kf   = (float*) alloc((size_t)M_ * 1024 * sizeof(float));
  f16*    vh   = (f16*)   alloc((size_t)M_ * 1024 * sizeof(f16));
  float4* tot  = (float4*)alloc((size_t)64 * B_ * H_ * D_ * sizeof(float4));
  f16*    yh   = xh;  // xh last read by GEMM1; scan_out writes y after

  hipFuncSetAttribute(reinterpret_cast<const void*>(&k_gemm8<4>),
                      hipFuncAttributeMaxDynamicSharedMemorySize, 131072);
  hipFuncSetAttribute(reinterpret_cast<const void*>(&k_gemm8<2>),
                      hipFuncAttributeMaxDynamicSharedMemorySize, 98304);

  hipLaunchKernelGGL(k_prep, dim3(32, 32, 4), dim3(32, 8), 0, stream,
                     x, Wk, Wv, Wo, xh, Wkvt, Wot);
  // [k_real | v] = x @ [Wk | Wv]  (cols<1024 -> kf f32, cols>=1024 -> vh f16)
  hipLaunchKernelGGL(k_gemm8<4>, dim3(32, 8), dim3(512), 131072, stream, xh, Wkvt, kf, vh);
  hipLaunchKernelGGL(k_scan_part, dim3(512), dim3(256), 0, stream, kf, vh, freqs, tot);
  hipLaunchKernelGGL(k_scan_out,  dim3(512), dim3(256), 0, stream, kf, vh, freqs, tot, gate, yh);
  // out = y @ Wo  (BM=128 -> grid 64x4 = 256 blocks, full GPU)
  hipLaunchKernelGGL(k_gemm8<2>, dim3(64, 4), dim3(512), 98304, stream, yh, Wot, out, nullptr);
}